// Round 1
// baseline (6593.768 us; speedup 1.0000x reference)
//
#include <hip/hip_runtime.h>

#define BATCH 2048
#define FEAT  768
#define NIND  1024
#define NCLS  16

// K1: phi = sqrt(2/N) * cos(2*(x@W + b)); writes phi [B][N] and phiT [N][B]
__global__ __launch_bounds__(256) void phi_kernel(
    const float* __restrict__ x, const float* __restrict__ rw,
    const float* __restrict__ rb, float* __restrict__ phi,
    float* __restrict__ phiT)
{
  __shared__ float xs[64][17];
  __shared__ float wsh[16][68];
  __shared__ float ts[64][65];
  const int b0 = blockIdx.x * 64, i0 = blockIdx.y * 64;
  const int tid = threadIdx.x;
  const int tr = tid >> 4, tc = tid & 15;
  float acc[4][4] = {};
  for (int k0 = 0; k0 < FEAT; k0 += 16) {
    {
      int bb = tid >> 2, kk = (tid & 3) << 2;
      float4 v = *(const float4*)(x + (size_t)(b0 + bb) * FEAT + k0 + kk);
      xs[bb][kk] = v.x; xs[bb][kk+1] = v.y; xs[bb][kk+2] = v.z; xs[bb][kk+3] = v.w;
      int k2 = tid >> 4, ii = (tid & 15) << 2;
      *(float4*)(&wsh[k2][ii]) = *(const float4*)(rw + (size_t)(k0 + k2) * NIND + i0 + ii);
    }
    __syncthreads();
    #pragma unroll
    for (int q = 0; q < 16; ++q) {
      float a[4];
      #pragma unroll
      for (int r = 0; r < 4; ++r) a[r] = xs[tr*4+r][q];
      float4 b4 = *(const float4*)(&wsh[q][tc*4]);
      float bv[4] = {b4.x, b4.y, b4.z, b4.w};
      #pragma unroll
      for (int r = 0; r < 4; ++r)
        #pragma unroll
        for (int c = 0; c < 4; ++c) acc[r][c] += a[r] * bv[c];
    }
    __syncthreads();
  }
  const float SC = 0.04419417382415922f;   // sqrt(2/1024)
  float4 rb4 = *(const float4*)(rb + i0 + tc*4);
  float rbl[4] = {rb4.x, rb4.y, rb4.z, rb4.w};
  #pragma unroll
  for (int r = 0; r < 4; ++r) {
    float vals[4];
    #pragma unroll
    for (int c = 0; c < 4; ++c) {
      float pr = 2.0f * (acc[r][c] + rbl[c]);
      vals[c] = SC * cosf(pr);
      ts[tr*4+r][tc*4+c] = vals[c];
    }
    float4 o = make_float4(vals[0], vals[1], vals[2], vals[3]);
    *(float4*)(phi + (size_t)(b0 + tr*4 + r) * NIND + i0 + tc*4) = o;
  }
  __syncthreads();
  #pragma unroll
  for (int rep = 0; rep < 4; ++rep) {
    int ii = tr*4 + rep;
    int bb2 = tc*4;
    float4 o = make_float4(ts[bb2][ii], ts[bb2+1][ii], ts[bb2+2][ii], ts[bb2+3][ii]);
    *(float4*)(phiT + (size_t)(i0 + ii) * BATCH + b0 + bb2) = o;
  }
}

// K2: logits[b][k] = phi[b]·beta_w[k] + beta_b[k]; softmax -> wmat[k][b] = p(1-p)
__global__ __launch_bounds__(256) void logits_kernel(
    const float* __restrict__ phi, const float* __restrict__ bw,
    const float* __restrict__ bbias, float* __restrict__ out,
    float* __restrict__ wmat)
{
  __shared__ float red[256][16];
  const int b = blockIdx.x, tid = threadIdx.x;
  float acc[16] = {};
  for (int i = tid; i < NIND; i += 256) {
    float ph = phi[(size_t)b * NIND + i];
    #pragma unroll
    for (int k = 0; k < 16; ++k) acc[k] += ph * bw[k * NIND + i];
  }
  #pragma unroll
  for (int k = 0; k < 16; ++k) red[tid][k] = acc[k];
  __syncthreads();
  for (int off = 128; off > 0; off >>= 1) {
    if (tid < off) {
      #pragma unroll
      for (int k = 0; k < 16; ++k) red[tid][k] += red[tid + off][k];
    }
    __syncthreads();
  }
  if (tid == 0) {
    float lg[16], mx = -1e30f;
    #pragma unroll
    for (int k = 0; k < 16; ++k) { lg[k] = red[0][k] + bbias[k]; mx = fmaxf(mx, lg[k]); }
    float s = 0.f, ex[16];
    #pragma unroll
    for (int k = 0; k < 16; ++k) { ex[k] = expf(lg[k] - mx); s += ex[k]; }
    float inv = 1.0f / s;
    #pragma unroll
    for (int k = 0; k < 16; ++k) {
      out[(size_t)b * NCLS + k] = lg[k];
      float p = ex[k] * inv;
      wmat[(size_t)k * BATCH + b] = p * (1.0f - p);
    }
  }
}

// K3: P[k] = prec_in[k] + sum_b w[k][b]*phi[b][i]*phi[b][j]  (symmetric, pair-tiled)
__global__ __launch_bounds__(256) void gram_kernel(
    const float* __restrict__ phi, const float* __restrict__ wmat,
    const float* __restrict__ prec, float* __restrict__ P)
{
  __shared__ float ua[16][65];
  __shared__ float ub[16][65];
  __shared__ float ts[64][65];
  int p = blockIdx.x;
  int ti = (int)((sqrtf(8.f * p + 1.f) - 1.f) * 0.5f);
  while ((ti + 1) * (ti + 2) / 2 <= p) ++ti;
  while (ti * (ti + 1) / 2 > p) --ti;
  int tj = p - ti * (ti + 1) / 2;
  const int k = blockIdx.y;
  const int i0 = ti * 64, j0 = tj * 64;
  const int tid = threadIdx.x, tr = tid >> 4, tc = tid & 15;
  const int lbb = tid >> 4, lii = (tid & 15) << 2;
  float acc[4][4] = {};
  for (int b0 = 0; b0 < BATCH; b0 += 16) {
    float w = wmat[(size_t)k * BATCH + b0 + lbb];
    float4 va = *(const float4*)(phi + (size_t)(b0 + lbb) * NIND + i0 + lii);
    ua[lbb][lii] = w * va.x; ua[lbb][lii+1] = w * va.y; ua[lbb][lii+2] = w * va.z; ua[lbb][lii+3] = w * va.w;
    float4 vb = *(const float4*)(phi + (size_t)(b0 + lbb) * NIND + j0 + lii);
    ub[lbb][lii] = vb.x; ub[lbb][lii+1] = vb.y; ub[lbb][lii+2] = vb.z; ub[lbb][lii+3] = vb.w;
    __syncthreads();
    #pragma unroll
    for (int q = 0; q < 16; ++q) {
      float a[4], bv[4];
      #pragma unroll
      for (int r = 0; r < 4; ++r) a[r] = ua[q][tr*4+r];
      #pragma unroll
      for (int c = 0; c < 4; ++c) bv[c] = ub[q][tc*4+c];
      #pragma unroll
      for (int r = 0; r < 4; ++r)
        #pragma unroll
        for (int c = 0; c < 4; ++c) acc[r][c] += a[r] * bv[c];
    }
    __syncthreads();
  }
  const size_t base = (size_t)k * NIND * NIND;
  #pragma unroll
  for (int r = 0; r < 4; ++r) {
    int gi = i0 + tr*4 + r;
    #pragma unroll
    for (int c = 0; c < 4; ++c) {
      int gj = j0 + tc*4 + c;
      ts[tr*4+r][tc*4+c] = acc[r][c];
      P[base + (size_t)gi * NIND + gj] = acc[r][c] + prec[base + (size_t)gi * NIND + gj];
    }
  }
  if (ti != tj) {
    __syncthreads();
    #pragma unroll
    for (int rep = 0; rep < 4; ++rep) {
      int jj = tr*4 + rep;
      int gj = j0 + jj;
      float tmp[4];
      #pragma unroll
      for (int cc = 0; cc < 4; ++cc) {
        int gi = i0 + tc*4 + cc;
        tmp[cc] = ts[tc*4+cc][jj] + prec[base + (size_t)gj * NIND + gi];
      }
      float4 o = make_float4(tmp[0], tmp[1], tmp[2], tmp[3]);
      *(float4*)(P + base + (size_t)gj * NIND + i0 + tc*4) = o;
    }
  }
}

// K4: factor 128x128 diag block (iter it) in LDS; also invert it (lower-tri) -> invL
__global__ __launch_bounds__(256) void potrf_kernel(
    float* __restrict__ P, float* __restrict__ invL, int it)
{
  __shared__ float D[128][129];
  __shared__ float W[128][128];
  __shared__ float diagL[128];
  const int k = blockIdx.x, tid = threadIdx.x;
  const size_t base = (size_t)k * NIND * NIND + (size_t)(it * 128) * NIND + it * 128;
  for (int t = tid; t < 128 * 128; t += 256) {
    int r = t >> 7, c = t & 127;
    D[r][c] = P[base + (size_t)r * NIND + c];
  }
  __syncthreads();
  for (int j = 0; j < 128; ++j) {
    float sj = sqrtf(D[j][j]);       // everyone reads; nobody writes D[j][j]
    float isj = 1.0f / sj;
    if (tid == 0) diagL[j] = sj;
    if (tid > j && tid < 128) D[tid][j] *= isj;
    __syncthreads();
    {
      int row = tid & 127, half = tid >> 7;
      if (row > j) {
        float lr = D[row][j];
        for (int c = j + 1 + half; c < 128; c += 2)
          D[row][c] -= lr * D[c][j];
      }
    }
    __syncthreads();
  }
  // row-sweep lower-triangular inversion: W = L^{-1} (dense, zeros above diag)
  for (int r = 0; r < 128; ++r) {
    if (tid < 128) {
      int c = tid;
      float s = 0.f;
      for (int j = c; j < r; ++j) s += D[r][j] * W[j][c];
      float v = ((c == r) ? 1.0f : 0.0f) - s;
      W[r][c] = (c <= r) ? (v / diagL[r]) : 0.0f;
    }
    __syncthreads();
  }
  for (int t = tid; t < 128 * 128; t += 256)
    invL[((size_t)k * 8 + it) * 16384 + t] = W[t >> 7][t & 127];
}

// K5: panel trsm: L21 = A21 * invL11^T  (in place; each wg owns 64 rows x full 128 cols)
__global__ __launch_bounds__(256) void trsm_kernel(
    float* __restrict__ P, const float* __restrict__ invL, int it)
{
  __shared__ float As[64][17];
  __shared__ float Ls[128][17];
  const int k = blockIdx.y;
  const int r0 = (it + 1) * 128 + blockIdx.x * 64;
  const int jb = it * 128;
  const int tid = threadIdx.x, tr = tid >> 4, tc = tid & 15;
  const size_t pb = (size_t)k * NIND * NIND;
  const float* invb = invL + ((size_t)k * 8 + it) * 16384;
  float acc[4][8] = {};
  for (int j0 = 0; j0 < 128; j0 += 16) {
    {
      int rr = tid >> 2, jj = (tid & 3) << 2;
      float4 v = *(const float4*)(P + pb + (size_t)(r0 + rr) * NIND + jb + j0 + jj);
      As[rr][jj] = v.x; As[rr][jj+1] = v.y; As[rr][jj+2] = v.z; As[rr][jj+3] = v.w;
      #pragma unroll
      for (int t = 0; t < 2; ++t) {
        int f = tid + t * 256;
        int r2 = f >> 2, j2 = (f & 3) << 2;
        float4 u = *(const float4*)(invb + (size_t)r2 * 128 + j0 + j2);
        Ls[r2][j2] = u.x; Ls[r2][j2+1] = u.y; Ls[r2][j2+2] = u.z; Ls[r2][j2+3] = u.w;
      }
    }
    __syncthreads();
    #pragma unroll
    for (int q = 0; q < 16; ++q) {
      float a[4];
      #pragma unroll
      for (int r = 0; r < 4; ++r) a[r] = As[tr*4+r][q];
      #pragma unroll
      for (int c = 0; c < 8; ++c) {
        float lv = Ls[tc*8+c][q];
        #pragma unroll
        for (int r = 0; r < 4; ++r) acc[r][c] += a[r] * lv;
      }
    }
    __syncthreads();
  }
  #pragma unroll
  for (int r = 0; r < 4; ++r) {
    #pragma unroll
    for (int c0 = 0; c0 < 8; c0 += 4) {
      float4 o = make_float4(acc[r][c0], acc[r][c0+1], acc[r][c0+2], acc[r][c0+3]);
      *(float4*)(P + pb + (size_t)(r0 + tr*4 + r) * NIND + jb + tc*8 + c0) = o;
    }
  }
}

// K6: trailing update A22 -= L21 L21^T (lower 64-tile pairs only)
__global__ __launch_bounds__(256) void syrk_kernel(float* __restrict__ P, int it)
{
  __shared__ float Pa[64][17];
  __shared__ float Pb[64][17];
  int p = blockIdx.x;
  int a = (int)((sqrtf(8.f * p + 1.f) - 1.f) * 0.5f);
  while ((a + 1) * (a + 2) / 2 <= p) ++a;
  while (a * (a + 1) / 2 > p) --a;
  int b = p - a * (a + 1) / 2;
  const int tbase = (it + 1) * 2;
  const int r0 = (tbase + a) * 64, c0 = (tbase + b) * 64;
  const int jb = it * 128;
  const int k = blockIdx.y;
  const size_t pb = (size_t)k * NIND * NIND;
  const int tid = threadIdx.x, tr = tid >> 4, tc = tid & 15;
  float acc[4][4] = {};
  for (int j0 = 0; j0 < 128; j0 += 16) {
    int rr = tid >> 2, jj = (tid & 3) << 2;
    float4 v = *(const float4*)(P + pb + (size_t)(r0 + rr) * NIND + jb + j0 + jj);
    Pa[rr][jj] = v.x; Pa[rr][jj+1] = v.y; Pa[rr][jj+2] = v.z; Pa[rr][jj+3] = v.w;
    float4 u = *(const float4*)(P + pb + (size_t)(c0 + rr) * NIND + jb + j0 + jj);
    Pb[rr][jj] = u.x; Pb[rr][jj+1] = u.y; Pb[rr][jj+2] = u.z; Pb[rr][jj+3] = u.w;
    __syncthreads();
    #pragma unroll
    for (int q = 0; q < 16; ++q) {
      float av[4], bv[4];
      #pragma unroll
      for (int r = 0; r < 4; ++r) av[r] = Pa[tr*4+r][q];
      #pragma unroll
      for (int c = 0; c < 4; ++c) bv[c] = Pb[tc*4+c][q];
      #pragma unroll
      for (int r = 0; r < 4; ++r)
        #pragma unroll
        for (int c = 0; c < 4; ++c) acc[r][c] += av[r] * bv[c];
    }
    __syncthreads();
  }
  #pragma unroll
  for (int r = 0; r < 4; ++r) {
    float* dst = P + pb + (size_t)(r0 + tr*4 + r) * NIND + c0 + tc*4;
    float4 cur = *(float4*)dst;
    cur.x -= acc[r][0]; cur.y -= acc[r][1]; cur.z -= acc[r][2]; cur.w -= acc[r][3];
    *(float4*)dst = cur;
  }
}

// K7: blocked forward substitution step I:
//   Y_I = invL_II * (B_I - sum_{J<I} L_IJ Y_J), B_I = phiT[I*128 .. ][b]
//   accumulates column square-sums into out[32768 + b*16 + k]
__global__ __launch_bounds__(256) void solve_kernel(
    const float* __restrict__ P, const float* __restrict__ invL,
    const float* __restrict__ phiT, float* __restrict__ Y,
    float* __restrict__ out, int I, int kbase)
{
  __shared__ float Ls[128][17];
  __shared__ float Ys[16][68];
  __shared__ float Ts[128][68];
  __shared__ float pv[16][64];
  const int ks = blockIdx.y, k = kbase + ks;
  const int b0 = blockIdx.x * 64;
  const int tid = threadIdx.x, tr = tid >> 4, tc = tid & 15;
  const size_t pb = (size_t)k * NIND * NIND;
  float acc[8][4];
  #pragma unroll
  for (int rr = 0; rr < 8; ++rr) {
    float4 v = *(const float4*)(phiT + (size_t)(I*128 + tr*8 + rr) * BATCH + b0 + tc*4);
    acc[rr][0] = v.x; acc[rr][1] = v.y; acc[rr][2] = v.z; acc[rr][3] = v.w;
  }
  for (int J = 0; J < I; ++J) {
    const size_t yb = (size_t)ks * NIND * BATCH + (size_t)(J * 128) * BATCH;
    for (int j0 = 0; j0 < 128; j0 += 16) {
      #pragma unroll
      for (int t = 0; t < 2; ++t) {
        int f = tid + t * 256;
        int r2 = f >> 2, j2 = (f & 3) << 2;
        float4 u = *(const float4*)(P + pb + (size_t)(I*128 + r2) * NIND + J*128 + j0 + j2);
        Ls[r2][j2] = u.x; Ls[r2][j2+1] = u.y; Ls[r2][j2+2] = u.z; Ls[r2][j2+3] = u.w;
      }
      {
        int jj = tid >> 4, c4 = (tid & 15) << 2;
        *(float4*)(&Ys[jj][c4]) = *(const float4*)(Y + yb + (size_t)(j0 + jj) * BATCH + b0 + c4);
      }
      __syncthreads();
      #pragma unroll
      for (int q = 0; q < 16; ++q) {
        float yv[4];
        #pragma unroll
        for (int c = 0; c < 4; ++c) yv[c] = Ys[q][tc*4+c];
        #pragma unroll
        for (int rr = 0; rr < 8; ++rr) {
          float lv = Ls[tr*8+rr][q];
          #pragma unroll
          for (int c = 0; c < 4; ++c) acc[rr][c] -= lv * yv[c];
        }
      }
      __syncthreads();
    }
  }
  #pragma unroll
  for (int rr = 0; rr < 8; ++rr)
    *(float4*)(&Ts[tr*8+rr][tc*4]) = make_float4(acc[rr][0], acc[rr][1], acc[rr][2], acc[rr][3]);
  __syncthreads();
  const float* invb = invL + ((size_t)k * 8 + I) * 16384;
  float oa[8][4] = {};
  for (int j0 = 0; j0 < 128; j0 += 16) {
    #pragma unroll
    for (int t = 0; t < 2; ++t) {
      int f = tid + t * 256;
      int r2 = f >> 2, j2 = (f & 3) << 2;
      float4 u = *(const float4*)(invb + (size_t)r2 * 128 + j0 + j2);
      Ls[r2][j2] = u.x; Ls[r2][j2+1] = u.y; Ls[r2][j2+2] = u.z; Ls[r2][j2+3] = u.w;
    }
    __syncthreads();
    #pragma unroll
    for (int q = 0; q < 16; ++q) {
      float4 t4 = *(const float4*)(&Ts[j0+q][tc*4]);
      float tv[4] = {t4.x, t4.y, t4.z, t4.w};
      #pragma unroll
      for (int rr = 0; rr < 8; ++rr) {
        float lv = Ls[tr*8+rr][q];
        #pragma unroll
        for (int c = 0; c < 4; ++c) oa[rr][c] += lv * tv[c];
      }
    }
    __syncthreads();
  }
  const size_t yo = (size_t)ks * NIND * BATCH + (size_t)(I * 128) * BATCH;
  float vp[4] = {0.f, 0.f, 0.f, 0.f};
  #pragma unroll
  for (int rr = 0; rr < 8; ++rr) {
    *(float4*)(Y + yo + (size_t)(tr*8 + rr) * BATCH + b0 + tc*4) =
        make_float4(oa[rr][0], oa[rr][1], oa[rr][2], oa[rr][3]);
    #pragma unroll
    for (int c = 0; c < 4; ++c) vp[c] += oa[rr][c] * oa[rr][c];
  }
  #pragma unroll
  for (int c = 0; c < 4; ++c) pv[tr][tc*4+c] = vp[c];
  __syncthreads();
  if (tid < 64) {
    float s = 0.f;
    #pragma unroll
    for (int t = 0; t < 16; ++t) s += pv[t][tid];
    out[BATCH * NCLS + (size_t)(b0 + tid) * NCLS + k] += s;
  }
}

extern "C" void kernel_launch(void* const* d_in, const int* in_sizes, int n_in,
                              void* d_out, int out_size, void* d_ws, size_t ws_size,
                              hipStream_t stream)
{
  (void)in_sizes; (void)n_in;
  const float* x   = (const float*)d_in[0];
  const float* rw  = (const float*)d_in[1];
  const float* rb  = (const float*)d_in[2];
  const float* bw  = (const float*)d_in[3];
  const float* bb  = (const float*)d_in[4];
  const float* prc = (const float*)d_in[5];
  float* out = (float*)d_out;
  char* ws = (char*)d_ws;
  size_t off = 0;
  auto alloc = [&](size_t bytes) -> float* {
    void* p = ws + off;
    off = (off + bytes + 255) & ~(size_t)255;
    return (float*)p;
  };
  float* phi  = alloc((size_t)BATCH * NIND * 4);
  float* phiT = alloc((size_t)NIND * BATCH * 4);
  float* wmat = alloc((size_t)NCLS * BATCH * 4);
  float* P    = alloc((size_t)NCLS * NIND * NIND * 4);
  float* invL = alloc((size_t)NCLS * 8 * 128 * 128 * 4);
  const size_t per = (size_t)NIND * BATCH * 4;
  const size_t rem = (ws_size > off) ? (ws_size - off) : 0;
  int kc = 1;
  if (rem >= 16 * per) kc = 16;
  else if (rem >= 8 * per) kc = 8;
  else if (rem >= 4 * per) kc = 4;
  else if (rem >= 2 * per) kc = 2;
  float* Y = (float*)(ws + off);

  hipMemsetAsync(d_out, 0, (size_t)out_size * sizeof(float), stream);
  phi_kernel<<<dim3(BATCH/64, NIND/64), 256, 0, stream>>>(x, rw, rb, phi, phiT);
  logits_kernel<<<dim3(BATCH), 256, 0, stream>>>(phi, bw, bb, out, wmat);
  gram_kernel<<<dim3(136, NCLS), 256, 0, stream>>>(phi, wmat, prc, P);
  for (int it = 0; it < 8; ++it) {
    potrf_kernel<<<dim3(NCLS), 256, 0, stream>>>(P, invL, it);
    if (it < 7) {
      trsm_kernel<<<dim3((7 - it) * 2, NCLS), 256, 0, stream>>>(P, invL, it);
      int n = 14 - 2 * it;
      syrk_kernel<<<dim3(n * (n + 1) / 2, NCLS), 256, 0, stream>>>(P, it);
    }
  }
  for (int kb = 0; kb < NCLS; kb += kc) {
    for (int I = 0; I < 8; ++I) {
      solve_kernel<<<dim3(BATCH/64, kc), 256, 0, stream>>>(P, invL, phiT, Y, out, I, kb);
    }
  }
}

// Round 2
// 5086.426 us; speedup vs baseline: 1.2963x; 1.2963x over previous
//
#include <hip/hip_runtime.h>

#define BATCH 2048
#define FEAT  768
#define NIND  1024
#define NCLS  16

// K1: phi = sqrt(2/N) * cos(2*(x@W + b)); writes phi [B][N] and phiT [N][B]
__global__ __launch_bounds__(256) void phi_kernel(
    const float* __restrict__ x, const float* __restrict__ rw,
    const float* __restrict__ rb, float* __restrict__ phi,
    float* __restrict__ phiT)
{
  __shared__ float xs[64][17];
  __shared__ float wsh[16][68];
  __shared__ float ts[64][65];
  const int b0 = blockIdx.x * 64, i0 = blockIdx.y * 64;
  const int tid = threadIdx.x;
  const int tr = tid >> 4, tc = tid & 15;
  float acc[4][4] = {};
  for (int k0 = 0; k0 < FEAT; k0 += 16) {
    {
      int bb = tid >> 2, kk = (tid & 3) << 2;
      float4 v = *(const float4*)(x + (size_t)(b0 + bb) * FEAT + k0 + kk);
      xs[bb][kk] = v.x; xs[bb][kk+1] = v.y; xs[bb][kk+2] = v.z; xs[bb][kk+3] = v.w;
      int k2 = tid >> 4, ii = (tid & 15) << 2;
      *(float4*)(&wsh[k2][ii]) = *(const float4*)(rw + (size_t)(k0 + k2) * NIND + i0 + ii);
    }
    __syncthreads();
    #pragma unroll
    for (int q = 0; q < 16; ++q) {
      float a[4];
      #pragma unroll
      for (int r = 0; r < 4; ++r) a[r] = xs[tr*4+r][q];
      float4 b4 = *(const float4*)(&wsh[q][tc*4]);
      float bv[4] = {b4.x, b4.y, b4.z, b4.w};
      #pragma unroll
      for (int r = 0; r < 4; ++r)
        #pragma unroll
        for (int c = 0; c < 4; ++c) acc[r][c] += a[r] * bv[c];
    }
    __syncthreads();
  }
  const float SC = 0.04419417382415922f;   // sqrt(2/1024)
  float4 rb4 = *(const float4*)(rb + i0 + tc*4);
  float rbl[4] = {rb4.x, rb4.y, rb4.z, rb4.w};
  #pragma unroll
  for (int r = 0; r < 4; ++r) {
    float vals[4];
    #pragma unroll
    for (int c = 0; c < 4; ++c) {
      float pr = 2.0f * (acc[r][c] + rbl[c]);
      vals[c] = SC * cosf(pr);
      ts[tr*4+r][tc*4+c] = vals[c];
    }
    float4 o = make_float4(vals[0], vals[1], vals[2], vals[3]);
    *(float4*)(phi + (size_t)(b0 + tr*4 + r) * NIND + i0 + tc*4) = o;
  }
  __syncthreads();
  #pragma unroll
  for (int rep = 0; rep < 4; ++rep) {
    int ii = tr*4 + rep;
    int bb2 = tc*4;
    float4 o = make_float4(ts[bb2][ii], ts[bb2+1][ii], ts[bb2+2][ii], ts[bb2+3][ii]);
    *(float4*)(phiT + (size_t)(i0 + ii) * BATCH + b0 + bb2) = o;
  }
}

// K2: logits[b][k] = phi[b]·beta_w[k] + beta_b[k]; softmax -> wmat[k][b] = p(1-p)
__global__ __launch_bounds__(256) void logits_kernel(
    const float* __restrict__ phi, const float* __restrict__ bw,
    const float* __restrict__ bbias, float* __restrict__ out,
    float* __restrict__ wmat)
{
  __shared__ float red[256][16];
  const int b = blockIdx.x, tid = threadIdx.x;
  float acc[16] = {};
  for (int i = tid; i < NIND; i += 256) {
    float ph = phi[(size_t)b * NIND + i];
    #pragma unroll
    for (int k = 0; k < 16; ++k) acc[k] += ph * bw[k * NIND + i];
  }
  #pragma unroll
  for (int k = 0; k < 16; ++k) red[tid][k] = acc[k];
  __syncthreads();
  for (int off = 128; off > 0; off >>= 1) {
    if (tid < off) {
      #pragma unroll
      for (int k = 0; k < 16; ++k) red[tid][k] += red[tid + off][k];
    }
    __syncthreads();
  }
  if (tid == 0) {
    float lg[16], mx = -1e30f;
    #pragma unroll
    for (int k = 0; k < 16; ++k) { lg[k] = red[0][k] + bbias[k]; mx = fmaxf(mx, lg[k]); }
    float s = 0.f, ex[16];
    #pragma unroll
    for (int k = 0; k < 16; ++k) { ex[k] = expf(lg[k] - mx); s += ex[k]; }
    float inv = 1.0f / s;
    #pragma unroll
    for (int k = 0; k < 16; ++k) {
      out[(size_t)b * NCLS + k] = lg[k];
      float p = ex[k] * inv;
      wmat[(size_t)k * BATCH + b] = p * (1.0f - p);
    }
  }
}

// K3 v2: all 16 classes per block. 32x32 (i,j) tile; products shared across classes.
__global__ __launch_bounds__(256) void gram_kernel(
    const float* __restrict__ phiT, const float* __restrict__ wmat,
    const float* __restrict__ prec, float* __restrict__ P)
{
  __shared__ float As[32][68];
  __shared__ float Bs[32][68];
  __shared__ float Ws[16][68];
  int p = blockIdx.x;
  int ti = (int)((sqrtf(8.f * p + 1.f) - 1.f) * 0.5f);
  while ((ti + 1) * (ti + 2) / 2 <= p) ++ti;
  while (ti * (ti + 1) / 2 > p) --ti;
  int tj = p - ti * (ti + 1) / 2;
  const int i0 = ti * 32, j0 = tj * 32;
  const int tid = threadIdx.x, tr = tid >> 4, tc = tid & 15;
  float acc[16][4] = {};
  for (int b0 = 0; b0 < BATCH; b0 += 64) {
    {
      int r = tid >> 3, cb = (tid & 7) << 3;   // 32 rows x 64 cols, 8 floats per thread
      float4 v0 = *(const float4*)(phiT + (size_t)(i0 + r) * BATCH + b0 + cb);
      float4 v1 = *(const float4*)(phiT + (size_t)(i0 + r) * BATCH + b0 + cb + 4);
      *(float4*)(&As[r][cb]) = v0; *(float4*)(&As[r][cb+4]) = v1;
      float4 u0 = *(const float4*)(phiT + (size_t)(j0 + r) * BATCH + b0 + cb);
      float4 u1 = *(const float4*)(phiT + (size_t)(j0 + r) * BATCH + b0 + cb + 4);
      *(float4*)(&Bs[r][cb]) = u0; *(float4*)(&Bs[r][cb+4]) = u1;
      int wk = tid >> 4, wb = (tid & 15) << 2;
      *(float4*)(&Ws[wk][wb]) = *(const float4*)(wmat + (size_t)wk * BATCH + b0 + wb);
    }
    __syncthreads();
    #pragma unroll
    for (int bc = 0; bc < 64; bc += 4) {
      float4 a0 = *(const float4*)(&As[tr*2    ][bc]);
      float4 a1 = *(const float4*)(&As[tr*2 + 1][bc]);
      float4 b0v = *(const float4*)(&Bs[tc*2    ][bc]);
      float4 b1v = *(const float4*)(&Bs[tc*2 + 1][bc]);
      float p00[4] = {a0.x*b0v.x, a0.y*b0v.y, a0.z*b0v.z, a0.w*b0v.w};
      float p01[4] = {a0.x*b1v.x, a0.y*b1v.y, a0.z*b1v.z, a0.w*b1v.w};
      float p10[4] = {a1.x*b0v.x, a1.y*b0v.y, a1.z*b0v.z, a1.w*b0v.w};
      float p11[4] = {a1.x*b1v.x, a1.y*b1v.y, a1.z*b1v.z, a1.w*b1v.w};
      #pragma unroll
      for (int k = 0; k < 16; ++k) {
        float4 wv = *(const float4*)(&Ws[k][bc]);
        acc[k][0] += wv.x*p00[0] + wv.y*p00[1] + wv.z*p00[2] + wv.w*p00[3];
        acc[k][1] += wv.x*p01[0] + wv.y*p01[1] + wv.z*p01[2] + wv.w*p01[3];
        acc[k][2] += wv.x*p10[0] + wv.y*p10[1] + wv.z*p10[2] + wv.w*p10[3];
        acc[k][3] += wv.x*p11[0] + wv.y*p11[1] + wv.z*p11[2] + wv.w*p11[3];
      }
    }
    __syncthreads();
  }
  const size_t ks = (size_t)NIND * NIND;
  #pragma unroll
  for (int k = 0; k < 16; ++k) {
    #pragma unroll
    for (int e = 0; e < 4; ++e) {
      int gi = i0 + tr*2 + (e >> 1), gj = j0 + tc*2 + (e & 1);
      size_t idx = (size_t)k * ks + (size_t)gi * NIND + gj;
      P[idx] = acc[k][e] + prec[idx];
      if (ti != tj) {
        size_t idx2 = (size_t)k * ks + (size_t)gj * NIND + gi;
        P[idx2] = acc[k][e] + prec[idx2];
      }
    }
  }
}

// K4 v2: factor 128x128 diag block + blocked triangular inverse, 1024 threads
__global__ __launch_bounds__(1024) void potrf_kernel(
    float* __restrict__ P, float* __restrict__ invL, int it)
{
  __shared__ float D[128][129];
  __shared__ float W[128][132];
  __shared__ float sdiag[128];
  __shared__ float sinv[128];
  __shared__ float Tmp[3][32][33];
  const int k = blockIdx.x, tid = threadIdx.x;
  const size_t base = (size_t)k * NIND * NIND + (size_t)(it * 128) * NIND + it * 128;
  for (int t = tid; t < 128 * 128; t += 1024)
    D[t >> 7][t & 127] = P[base + (size_t)(t >> 7) * NIND + (t & 127)];
  __syncthreads();
  const int row = tid & 127, q = tid >> 7;
  // division-scaled right-looking factor (lower triangle only):
  // D[r][c] -= D[r][j]*D[c][j]/D[j][j]; scale at end.
  for (int j = 0; j < 127; ++j) {
    if (row > j) {
      float invd = 1.0f / D[j][j];
      float lr = D[row][j] * invd;
      for (int c = j + 1 + q; c <= row; c += 8)
        D[row][c] -= lr * D[c][j];
    }
    __syncthreads();
  }
  if (tid < 128) {
    float d = D[tid][tid];
    float s = sqrtf(d);
    sdiag[tid] = s;
    sinv[tid] = 1.0f / s;
  }
  __syncthreads();
  // scale to L
  for (int t = tid; t < 128 * 128; t += 1024) {
    int r = t >> 7, c = t & 127;
    if (r > c) D[r][c] *= sinv[c];
    else if (r == c) D[r][c] = sdiag[c];
  }
  __syncthreads();
  // phase A: invert 4 diagonal 32x32 blocks (one column per thread, independent)
  if (tid < 128) {
    int blk = tid >> 5, c = tid & 31, b0 = blk * 32;
    for (int r = 0; r < 32; ++r) {
      if (r < c) { W[b0 + r][b0 + c] = 0.f; }
      else {
        float s = 0.f;
        for (int j = c; j < r; ++j) s += D[b0 + r][b0 + j] * W[b0 + j][b0 + c];
        float v = ((r == c) ? 1.0f : 0.0f) - s;
        W[b0 + r][b0 + c] = v * sinv[b0 + r];
      }
    }
  }
  __syncthreads();
  // phase B: off-diag blocks W_IJ = -W_II * (sum_{K=J}^{I-1} L_IK W_KJ), 3 levels
  for (int d = 1; d <= 3; ++d) {
    int nb = 4 - d;
    for (int t = tid; t < nb * 1024; t += 1024) {
      int bi = t >> 10, rc = t & 1023, r = rc >> 5, c = rc & 31;
      int J = bi, I = J + d;
      float s = 0.f;
      for (int K = J; K < I; ++K)
        #pragma unroll 8
        for (int j = 0; j < 32; ++j)
          s += D[I*32 + r][K*32 + j] * W[K*32 + j][J*32 + c];
      Tmp[bi][r][c] = s;
    }
    __syncthreads();
    for (int t = tid; t < nb * 1024; t += 1024) {
      int bi = t >> 10, rc = t & 1023, r = rc >> 5, c = rc & 31;
      int J = bi, I = J + d;
      float s = 0.f;
      for (int j = 0; j <= r; ++j)
        s += W[I*32 + r][I*32 + j] * Tmp[bi][j][c];
      W[I*32 + r][J*32 + c] = -s;
    }
    __syncthreads();
  }
  for (int t = tid; t < 128 * 128; t += 1024) {
    int r = t >> 7, c = t & 127;
    invL[((size_t)k * 8 + it) * 16384 + t] = (c <= r) ? W[r][c] : 0.f;
  }
}

// K5: panel trsm: L21 = A21 * invL11^T  (in place; each wg owns 64 rows x full 128 cols)
__global__ __launch_bounds__(256) void trsm_kernel(
    float* __restrict__ P, const float* __restrict__ invL, int it)
{
  __shared__ float As[64][17];
  __shared__ float Ls[128][17];
  const int k = blockIdx.y;
  const int r0 = (it + 1) * 128 + blockIdx.x * 64;
  const int jb = it * 128;
  const int tid = threadIdx.x, tr = tid >> 4, tc = tid & 15;
  const size_t pb = (size_t)k * NIND * NIND;
  const float* invb = invL + ((size_t)k * 8 + it) * 16384;
  float acc[4][8] = {};
  for (int j0 = 0; j0 < 128; j0 += 16) {
    {
      int rr = tid >> 2, jj = (tid & 3) << 2;
      float4 v = *(const float4*)(P + pb + (size_t)(r0 + rr) * NIND + jb + j0 + jj);
      As[rr][jj] = v.x; As[rr][jj+1] = v.y; As[rr][jj+2] = v.z; As[rr][jj+3] = v.w;
      #pragma unroll
      for (int t = 0; t < 2; ++t) {
        int f = tid + t * 256;
        int r2 = f >> 2, j2 = (f & 3) << 2;
        float4 u = *(const float4*)(invb + (size_t)r2 * 128 + j0 + j2);
        Ls[r2][j2] = u.x; Ls[r2][j2+1] = u.y; Ls[r2][j2+2] = u.z; Ls[r2][j2+3] = u.w;
      }
    }
    __syncthreads();
    #pragma unroll
    for (int qq = 0; qq < 16; ++qq) {
      float a[4];
      #pragma unroll
      for (int r = 0; r < 4; ++r) a[r] = As[tr*4+r][qq];
      #pragma unroll
      for (int c = 0; c < 8; ++c) {
        float lv = Ls[tc*8+c][qq];
        #pragma unroll
        for (int r = 0; r < 4; ++r) acc[r][c] += a[r] * lv;
      }
    }
    __syncthreads();
  }
  #pragma unroll
  for (int r = 0; r < 4; ++r) {
    #pragma unroll
    for (int c0 = 0; c0 < 8; c0 += 4) {
      float4 o = make_float4(acc[r][c0], acc[r][c0+1], acc[r][c0+2], acc[r][c0+3]);
      *(float4*)(P + pb + (size_t)(r0 + tr*4 + r) * NIND + jb + tc*8 + c0) = o;
    }
  }
}

// K6: trailing update A22 -= L21 L21^T (lower 64-tile pairs only)
__global__ __launch_bounds__(256) void syrk_kernel(float* __restrict__ P, int it)
{
  __shared__ float Pa[64][17];
  __shared__ float Pb[64][17];
  int p = blockIdx.x;
  int a = (int)((sqrtf(8.f * p + 1.f) - 1.f) * 0.5f);
  while ((a + 1) * (a + 2) / 2 <= p) ++a;
  while (a * (a + 1) / 2 > p) --a;
  int b = p - a * (a + 1) / 2;
  const int tbase = (it + 1) * 2;
  const int r0 = (tbase + a) * 64, c0 = (tbase + b) * 64;
  const int jb = it * 128;
  const int k = blockIdx.y;
  const size_t pb = (size_t)k * NIND * NIND;
  const int tid = threadIdx.x, tr = tid >> 4, tc = tid & 15;
  float acc[4][4] = {};
  for (int j0 = 0; j0 < 128; j0 += 16) {
    int rr = tid >> 2, jj = (tid & 3) << 2;
    float4 v = *(const float4*)(P + pb + (size_t)(r0 + rr) * NIND + jb + j0 + jj);
    Pa[rr][jj] = v.x; Pa[rr][jj+1] = v.y; Pa[rr][jj+2] = v.z; Pa[rr][jj+3] = v.w;
    float4 u = *(const float4*)(P + pb + (size_t)(c0 + rr) * NIND + jb + j0 + jj);
    Pb[rr][jj] = u.x; Pb[rr][jj+1] = u.y; Pb[rr][jj+2] = u.z; Pb[rr][jj+3] = u.w;
    __syncthreads();
    #pragma unroll
    for (int qq = 0; qq < 16; ++qq) {
      float av[4], bv[4];
      #pragma unroll
      for (int r = 0; r < 4; ++r) av[r] = Pa[tr*4+r][qq];
      #pragma unroll
      for (int c = 0; c < 4; ++c) bv[c] = Pb[tc*4+c][qq];
      #pragma unroll
      for (int r = 0; r < 4; ++r)
        #pragma unroll
        for (int c = 0; c < 4; ++c) acc[r][c] += av[r] * bv[c];
    }
    __syncthreads();
  }
  #pragma unroll
  for (int r = 0; r < 4; ++r) {
    float* dst = P + pb + (size_t)(r0 + tr*4 + r) * NIND + c0 + tc*4;
    float4 cur = *(float4*)dst;
    cur.x -= acc[r][0]; cur.y -= acc[r][1]; cur.z -= acc[r][2]; cur.w -= acc[r][3];
    *(float4*)dst = cur;
  }
}

// K7: blocked forward substitution step I (unchanged)
__global__ __launch_bounds__(256) void solve_kernel(
    const float* __restrict__ P, const float* __restrict__ invL,
    const float* __restrict__ phiT, float* __restrict__ Y,
    float* __restrict__ out, int I, int kbase)
{
  __shared__ float Ls[128][17];
  __shared__ float Ys[16][68];
  __shared__ float Ts[128][68];
  __shared__ float pv[16][64];
  const int ks = blockIdx.y, k = kbase + ks;
  const int b0 = blockIdx.x * 64;
  const int tid = threadIdx.x, tr = tid >> 4, tc = tid & 15;
  const size_t pb = (size_t)k * NIND * NIND;
  float acc[8][4];
  #pragma unroll
  for (int rr = 0; rr < 8; ++rr) {
    float4 v = *(const float4*)(phiT + (size_t)(I*128 + tr*8 + rr) * BATCH + b0 + tc*4);
    acc[rr][0] = v.x; acc[rr][1] = v.y; acc[rr][2] = v.z; acc[rr][3] = v.w;
  }
  for (int J = 0; J < I; ++J) {
    const size_t yb = (size_t)ks * NIND * BATCH + (size_t)(J * 128) * BATCH;
    for (int j0 = 0; j0 < 128; j0 += 16) {
      #pragma unroll
      for (int t = 0; t < 2; ++t) {
        int f = tid + t * 256;
        int r2 = f >> 2, j2 = (f & 3) << 2;
        float4 u = *(const float4*)(P + pb + (size_t)(I*128 + r2) * NIND + J*128 + j0 + j2);
        Ls[r2][j2] = u.x; Ls[r2][j2+1] = u.y; Ls[r2][j2+2] = u.z; Ls[r2][j2+3] = u.w;
      }
      {
        int jj = tid >> 4, c4 = (tid & 15) << 2;
        *(float4*)(&Ys[jj][c4]) = *(const float4*)(Y + yb + (size_t)(j0 + jj) * BATCH + b0 + c4);
      }
      __syncthreads();
      #pragma unroll
      for (int qq = 0; qq < 16; ++qq) {
        float yv[4];
        #pragma unroll
        for (int c = 0; c < 4; ++c) yv[c] = Ys[qq][tc*4+c];
        #pragma unroll
        for (int rr = 0; rr < 8; ++rr) {
          float lv = Ls[tr*8+rr][qq];
          #pragma unroll
          for (int c = 0; c < 4; ++c) acc[rr][c] -= lv * yv[c];
        }
      }
      __syncthreads();
    }
  }
  #pragma unroll
  for (int rr = 0; rr < 8; ++rr)
    *(float4*)(&Ts[tr*8+rr][tc*4]) = make_float4(acc[rr][0], acc[rr][1], acc[rr][2], acc[rr][3]);
  __syncthreads();
  const float* invb = invL + ((size_t)k * 8 + I) * 16384;
  float oa[8][4] = {};
  for (int j0 = 0; j0 < 128; j0 += 16) {
    #pragma unroll
    for (int t = 0; t < 2; ++t) {
      int f = tid + t * 256;
      int r2 = f >> 2, j2 = (f & 3) << 2;
      float4 u = *(const float4*)(invb + (size_t)r2 * 128 + j0 + j2);
      Ls[r2][j2] = u.x; Ls[r2][j2+1] = u.y; Ls[r2][j2+2] = u.z; Ls[r2][j2+3] = u.w;
    }
    __syncthreads();
    #pragma unroll
    for (int qq = 0; qq < 16; ++qq) {
      float4 t4 = *(const float4*)(&Ts[j0+qq][tc*4]);
      float tv[4] = {t4.x, t4.y, t4.z, t4.w};
      #pragma unroll
      for (int rr = 0; rr < 8; ++rr) {
        float lv = Ls[tr*8+rr][qq];
        #pragma unroll
        for (int c = 0; c < 4; ++c) oa[rr][c] += lv * tv[c];
      }
    }
    __syncthreads();
  }
  const size_t yo = (size_t)ks * NIND * BATCH + (size_t)(I * 128) * BATCH;
  float vp[4] = {0.f, 0.f, 0.f, 0.f};
  #pragma unroll
  for (int rr = 0; rr < 8; ++rr) {
    *(float4*)(Y + yo + (size_t)(tr*8 + rr) * BATCH + b0 + tc*4) =
        make_float4(oa[rr][0], oa[rr][1], oa[rr][2], oa[rr][3]);
    #pragma unroll
    for (int c = 0; c < 4; ++c) vp[c] += oa[rr][c] * oa[rr][c];
  }
  #pragma unroll
  for (int c = 0; c < 4; ++c) pv[tr][tc*4+c] = vp[c];
  __syncthreads();
  if (tid < 64) {
    float s = 0.f;
    #pragma unroll
    for (int t = 0; t < 16; ++t) s += pv[t][tid];
    out[BATCH * NCLS + (size_t)(b0 + tid) * NCLS + k] += s;
  }
}

extern "C" void kernel_launch(void* const* d_in, const int* in_sizes, int n_in,
                              void* d_out, int out_size, void* d_ws, size_t ws_size,
                              hipStream_t stream)
{
  (void)in_sizes; (void)n_in;
  const float* x   = (const float*)d_in[0];
  const float* rw  = (const float*)d_in[1];
  const float* rb  = (const float*)d_in[2];
  const float* bw  = (const float*)d_in[3];
  const float* bb  = (const float*)d_in[4];
  const float* prc = (const float*)d_in[5];
  float* out = (float*)d_out;
  char* ws = (char*)d_ws;
  size_t off = 0;
  auto alloc = [&](size_t bytes) -> float* {
    void* p = ws + off;
    off = (off + bytes + 255) & ~(size_t)255;
    return (float*)p;
  };
  float* phi  = alloc((size_t)BATCH * NIND * 4);
  float* phiT = alloc((size_t)NIND * BATCH * 4);
  float* wmat = alloc((size_t)NCLS * BATCH * 4);
  float* P    = alloc((size_t)NCLS * NIND * NIND * 4);
  float* invL = alloc((size_t)NCLS * 8 * 128 * 128 * 4);
  const size_t per = (size_t)NIND * BATCH * 4;
  const size_t rem = (ws_size > off) ? (ws_size - off) : 0;
  int kc = 1;
  if (rem >= 16 * per) kc = 16;
  else if (rem >= 8 * per) kc = 8;
  else if (rem >= 4 * per) kc = 4;
  else if (rem >= 2 * per) kc = 2;
  float* Y = (float*)(ws + off);

  hipMemsetAsync(d_out, 0, (size_t)out_size * sizeof(float), stream);
  phi_kernel<<<dim3(BATCH/64, NIND/64), 256, 0, stream>>>(x, rw, rb, phi, phiT);
  logits_kernel<<<dim3(BATCH), 256, 0, stream>>>(phi, bw, bb, out, wmat);
  gram_kernel<<<dim3(528), 256, 0, stream>>>(phiT, wmat, prc, P);
  for (int it = 0; it < 8; ++it) {
    potrf_kernel<<<dim3(NCLS), 1024, 0, stream>>>(P, invL, it);
    if (it < 7) {
      trsm_kernel<<<dim3((7 - it) * 2, NCLS), 256, 0, stream>>>(P, invL, it);
      int n = 14 - 2 * it;
      syrk_kernel<<<dim3(n * (n + 1) / 2, NCLS), 256, 0, stream>>>(P, it);
    }
  }
  for (int kb = 0; kb < NCLS; kb += kc) {
    for (int I = 0; I < 8; ++I) {
      solve_kernel<<<dim3(BATCH/64, kc), 256, 0, stream>>>(P, invL, phiT, Y, out, I, kb);
    }
  }
}

// Round 3
// 2320.035 us; speedup vs baseline: 2.8421x; 2.1924x over previous
//
#include <hip/hip_runtime.h>

#define BATCH 2048
#define FEAT  768
#define NIND  1024
#define NCLS  16

typedef unsigned short u16;
typedef __attribute__((ext_vector_type(8))) __bf16 bf16x8;
typedef __attribute__((ext_vector_type(4))) float f32x4;

static __device__ __forceinline__ unsigned f2bf(float f) {
  unsigned u = __float_as_uint(f);
  unsigned r = ((u >> 16) & 1u) + 0x7FFFu;
  return (u + r) >> 16;                       // RNE bf16 in low 16 bits
}

// K1: phi = sqrt(2/N)*cos(2*(x@W+b)); writes phi [B][N], phiT [N][B] f32, phiTB [N][B] bf16
__global__ __launch_bounds__(256) void phi_kernel(
    const float* __restrict__ x, const float* __restrict__ rw,
    const float* __restrict__ rb, float* __restrict__ phi,
    float* __restrict__ phiT, u16* __restrict__ phiTB)
{
  __shared__ float xs[64][17];
  __shared__ float wsh[16][68];
  __shared__ float ts[64][65];
  const int b0 = blockIdx.x * 64, i0 = blockIdx.y * 64;
  const int tid = threadIdx.x;
  const int tr = tid >> 4, tc = tid & 15;
  float acc[4][4] = {};
  for (int k0 = 0; k0 < FEAT; k0 += 16) {
    {
      int bb = tid >> 2, kk = (tid & 3) << 2;
      float4 v = *(const float4*)(x + (size_t)(b0 + bb) * FEAT + k0 + kk);
      xs[bb][kk] = v.x; xs[bb][kk+1] = v.y; xs[bb][kk+2] = v.z; xs[bb][kk+3] = v.w;
      int k2 = tid >> 4, ii = (tid & 15) << 2;
      *(float4*)(&wsh[k2][ii]) = *(const float4*)(rw + (size_t)(k0 + k2) * NIND + i0 + ii);
    }
    __syncthreads();
    #pragma unroll
    for (int q = 0; q < 16; ++q) {
      float a[4];
      #pragma unroll
      for (int r = 0; r < 4; ++r) a[r] = xs[tr*4+r][q];
      float4 b4 = *(const float4*)(&wsh[q][tc*4]);
      float bv[4] = {b4.x, b4.y, b4.z, b4.w};
      #pragma unroll
      for (int r = 0; r < 4; ++r)
        #pragma unroll
        for (int c = 0; c < 4; ++c) acc[r][c] += a[r] * bv[c];
    }
    __syncthreads();
  }
  const float SC = 0.04419417382415922f;   // sqrt(2/1024)
  float4 rb4 = *(const float4*)(rb + i0 + tc*4);
  float rbl[4] = {rb4.x, rb4.y, rb4.z, rb4.w};
  #pragma unroll
  for (int r = 0; r < 4; ++r) {
    float vals[4];
    #pragma unroll
    for (int c = 0; c < 4; ++c) {
      float pr = 2.0f * (acc[r][c] + rbl[c]);
      vals[c] = SC * cosf(pr);
      ts[tr*4+r][tc*4+c] = vals[c];
    }
    float4 o = make_float4(vals[0], vals[1], vals[2], vals[3]);
    *(float4*)(phi + (size_t)(b0 + tr*4 + r) * NIND + i0 + tc*4) = o;
  }
  __syncthreads();
  #pragma unroll
  for (int rep = 0; rep < 4; ++rep) {
    int ii = tr*4 + rep;
    int bb2 = tc*4;
    float4 o = make_float4(ts[bb2][ii], ts[bb2+1][ii], ts[bb2+2][ii], ts[bb2+3][ii]);
    *(float4*)(phiT + (size_t)(i0 + ii) * BATCH + b0 + bb2) = o;
    uint2 ob;
    ob.x = (f2bf(o.x) & 0xFFFFu) | (f2bf(o.y) << 16);
    ob.y = (f2bf(o.z) & 0xFFFFu) | (f2bf(o.w) << 16);
    *(uint2*)(phiTB + (size_t)(i0 + ii) * BATCH + b0 + bb2) = ob;
  }
}

// K2: logits + softmax -> wmat[k][b] = p(1-p)
__global__ __launch_bounds__(256) void logits_kernel(
    const float* __restrict__ phi, const float* __restrict__ bw,
    const float* __restrict__ bbias, float* __restrict__ out,
    float* __restrict__ wmat)
{
  __shared__ float red[256][16];
  const int b = blockIdx.x, tid = threadIdx.x;
  float acc[16] = {};
  for (int i = tid; i < NIND; i += 256) {
    float ph = phi[(size_t)b * NIND + i];
    #pragma unroll
    for (int k = 0; k < 16; ++k) acc[k] += ph * bw[k * NIND + i];
  }
  #pragma unroll
  for (int k = 0; k < 16; ++k) red[tid][k] = acc[k];
  __syncthreads();
  for (int off = 128; off > 0; off >>= 1) {
    if (tid < off) {
      #pragma unroll
      for (int k = 0; k < 16; ++k) red[tid][k] += red[tid + off][k];
    }
    __syncthreads();
  }
  if (tid == 0) {
    float lg[16], mx = -1e30f;
    #pragma unroll
    for (int k = 0; k < 16; ++k) { lg[k] = red[0][k] + bbias[k]; mx = fmaxf(mx, lg[k]); }
    float s = 0.f, ex[16];
    #pragma unroll
    for (int k = 0; k < 16; ++k) { ex[k] = expf(lg[k] - mx); s += ex[k]; }
    float inv = 1.0f / s;
    #pragma unroll
    for (int k = 0; k < 16; ++k) {
      out[(size_t)b * NCLS + k] = lg[k];
      float p = ex[k] * inv;
      wmat[(size_t)k * BATCH + b] = p * (1.0f - p);
    }
  }
}

// K2b: phiW[k][i][b] = bf16(wmat[k][b] * phiT[i][b])
__global__ __launch_bounds__(256) void scalew_kernel(
    const float* __restrict__ phiT, const float* __restrict__ wmat,
    u16* __restrict__ phiW)
{
  const int k = blockIdx.y;
  size_t flat = ((size_t)blockIdx.x * 256 + threadIdx.x) * 8;
  int i = (int)(flat >> 11), b = (int)(flat & 2047);
  float4 p0 = *(const float4*)(phiT + (size_t)i * BATCH + b);
  float4 p1 = *(const float4*)(phiT + (size_t)i * BATCH + b + 4);
  float4 w0 = *(const float4*)(wmat + (size_t)k * BATCH + b);
  float4 w1 = *(const float4*)(wmat + (size_t)k * BATCH + b + 4);
  uint4 o;
  o.x = (f2bf(p0.x*w0.x) & 0xFFFFu) | (f2bf(p0.y*w0.y) << 16);
  o.y = (f2bf(p0.z*w0.z) & 0xFFFFu) | (f2bf(p0.w*w0.w) << 16);
  o.z = (f2bf(p1.x*w1.x) & 0xFFFFu) | (f2bf(p1.y*w1.y) << 16);
  o.w = (f2bf(p1.z*w1.z) & 0xFFFFu) | (f2bf(p1.w*w1.w) << 16);
  *(uint4*)(phiW + (size_t)k * NIND * BATCH + flat) = o;
}

// K3 v3: MFMA bf16 gram. C_k = phiW_k^T-view (M=i) x phiTB (N=j), K=batch.
// 128x128 tile per block, 4 waves 2x2, mfma_f32_16x16x32_bf16, BK=64.
__global__ __launch_bounds__(256) void gram_kernel(
    const u16* __restrict__ phiW, const u16* __restrict__ phiTB,
    const float* __restrict__ prec, float* __restrict__ P)
{
  __shared__ u16 Als[128 * 64];
  __shared__ u16 Bls[128 * 64];
  int p = blockIdx.x;                 // 36 lower tile-pairs of 8x8
  int ti = 0;
  while ((ti + 1) * (ti + 2) / 2 <= p) ++ti;
  int tj = p - ti * (ti + 1) / 2;
  const int k = blockIdx.y;
  const int i0 = ti * 128, j0 = tj * 128;
  const int tid = threadIdx.x;
  const int wid = tid >> 6, lane = tid & 63;
  const int wr = wid >> 1, wc = wid & 1;
  const u16* Ag = phiW + (size_t)k * NIND * BATCH + (size_t)i0 * BATCH;
  const u16* Bg = phiTB + (size_t)j0 * BATCH;
  f32x4 acc[4][4];
  #pragma unroll
  for (int m = 0; m < 4; ++m)
    #pragma unroll
    for (int n = 0; n < 4; ++n) acc[m][n] = (f32x4){0.f, 0.f, 0.f, 0.f};
  for (int b0 = 0; b0 < BATCH; b0 += 64) {
    #pragma unroll
    for (int c = 0; c < 4; ++c) {
      int f = c * 256 + tid;          // 0..1023 : row = f/8, 16B chunk = f%8
      int row = f >> 3, kc8 = f & 7;
      uint4 va = *(const uint4*)(Ag + (size_t)row * BATCH + b0 + kc8 * 8);
      uint4 vb = *(const uint4*)(Bg + (size_t)row * BATCH + b0 + kc8 * 8);
      int idx = (row * 64 + kc8 * 8) ^ ((row & 7) << 3);   // byte ^= (row&7)<<4
      *(uint4*)(&Als[idx]) = va;
      *(uint4*)(&Bls[idx]) = vb;
    }
    __syncthreads();
    #pragma unroll
    for (int ks = 0; ks < 2; ++ks) {
      bf16x8 af[4], bfr[4];
      #pragma unroll
      for (int m = 0; m < 4; ++m) {
        int row = wr * 64 + m * 16 + (lane & 15);
        int kb = ks * 32 + (lane >> 4) * 8;
        int idx = (row * 64 + kb) ^ ((row & 7) << 3);
        af[m] = *(const bf16x8*)(&Als[idx]);
      }
      #pragma unroll
      for (int n = 0; n < 4; ++n) {
        int row = wc * 64 + n * 16 + (lane & 15);
        int kb = ks * 32 + (lane >> 4) * 8;
        int idx = (row * 64 + kb) ^ ((row & 7) << 3);
        bfr[n] = *(const bf16x8*)(&Bls[idx]);
      }
      #pragma unroll
      for (int m = 0; m < 4; ++m)
        #pragma unroll
        for (int n = 0; n < 4; ++n)
          acc[m][n] = __builtin_amdgcn_mfma_f32_16x16x32_bf16(af[m], bfr[n], acc[m][n], 0, 0, 0);
    }
    __syncthreads();
  }
  const size_t kb2 = (size_t)k * NIND * NIND;
  #pragma unroll
  for (int m = 0; m < 4; ++m) {
    #pragma unroll
    for (int n = 0; n < 4; ++n) {
      #pragma unroll
      for (int r = 0; r < 4; ++r) {
        int gi = i0 + wr * 64 + m * 16 + (lane >> 4) * 4 + r;
        int gj = j0 + wc * 64 + n * 16 + (lane & 15);
        float v = acc[m][n][r];
        size_t idx = kb2 + (size_t)gi * NIND + gj;
        P[idx] = v + prec[idx];
        if (ti != tj) {
          size_t idx2 = kb2 + (size_t)gj * NIND + gi;
          P[idx2] = v + prec[idx2];
        }
      }
    }
  }
}

// K4: factor 128x128 diag block + blocked triangular inverse, 1024 threads
__global__ __launch_bounds__(1024) void potrf_kernel(
    float* __restrict__ P, float* __restrict__ invL, int it)
{
  __shared__ float D[128][129];
  __shared__ float W[128][132];
  __shared__ float sdiag[128];
  __shared__ float sinv[128];
  __shared__ float Tmp[3][32][33];
  const int k = blockIdx.x, tid = threadIdx.x;
  const size_t base = (size_t)k * NIND * NIND + (size_t)(it * 128) * NIND + it * 128;
  for (int t = tid; t < 128 * 128; t += 1024)
    D[t >> 7][t & 127] = P[base + (size_t)(t >> 7) * NIND + (t & 127)];
  __syncthreads();
  const int row = tid & 127, q = tid >> 7;
  for (int j = 0; j < 127; ++j) {
    if (row > j) {
      float invd = 1.0f / D[j][j];
      float lr = D[row][j] * invd;
      for (int c = j + 1 + q; c <= row; c += 8)
        D[row][c] -= lr * D[c][j];
    }
    __syncthreads();
  }
  if (tid < 128) {
    float d = D[tid][tid];
    float s = sqrtf(d);
    sdiag[tid] = s;
    sinv[tid] = 1.0f / s;
  }
  __syncthreads();
  for (int t = tid; t < 128 * 128; t += 1024) {
    int r = t >> 7, c = t & 127;
    if (r > c) D[r][c] *= sinv[c];
    else if (r == c) D[r][c] = sdiag[c];
  }
  __syncthreads();
  if (tid < 128) {
    int blk = tid >> 5, c = tid & 31, b0 = blk * 32;
    for (int r = 0; r < 32; ++r) {
      if (r < c) { W[b0 + r][b0 + c] = 0.f; }
      else {
        float s = 0.f;
        for (int j = c; j < r; ++j) s += D[b0 + r][b0 + j] * W[b0 + j][b0 + c];
        float v = ((r == c) ? 1.0f : 0.0f) - s;
        W[b0 + r][b0 + c] = v * sinv[b0 + r];
      }
    }
  }
  __syncthreads();
  for (int d = 1; d <= 3; ++d) {
    int nb = 4 - d;
    for (int t = tid; t < nb * 1024; t += 1024) {
      int bi = t >> 10, rc = t & 1023, r = rc >> 5, c = rc & 31;
      int J = bi, I = J + d;
      float s = 0.f;
      for (int K = J; K < I; ++K)
        #pragma unroll 8
        for (int j = 0; j < 32; ++j)
          s += D[I*32 + r][K*32 + j] * W[K*32 + j][J*32 + c];
      Tmp[bi][r][c] = s;
    }
    __syncthreads();
    for (int t = tid; t < nb * 1024; t += 1024) {
      int bi = t >> 10, rc = t & 1023, r = rc >> 5, c = rc & 31;
      int J = bi, I = J + d;
      float s = 0.f;
      for (int j = 0; j <= r; ++j)
        s += W[I*32 + r][I*32 + j] * Tmp[bi][j][c];
      W[I*32 + r][J*32 + c] = -s;
    }
    __syncthreads();
  }
  for (int t = tid; t < 128 * 128; t += 1024) {
    int r = t >> 7, c = t & 127;
    invL[((size_t)k * 8 + it) * 16384 + t] = (c <= r) ? W[r][c] : 0.f;
  }
}

// K5: panel trsm: L21 = A21 * invL11^T
__global__ __launch_bounds__(256) void trsm_kernel(
    float* __restrict__ P, const float* __restrict__ invL, int it)
{
  __shared__ float As[64][17];
  __shared__ float Ls[128][17];
  const int k = blockIdx.y;
  const int r0 = (it + 1) * 128 + blockIdx.x * 64;
  const int jb = it * 128;
  const int tid = threadIdx.x, tr = tid >> 4, tc = tid & 15;
  const size_t pb = (size_t)k * NIND * NIND;
  const float* invb = invL + ((size_t)k * 8 + it) * 16384;
  float acc[4][8] = {};
  for (int j0 = 0; j0 < 128; j0 += 16) {
    {
      int rr = tid >> 2, jj = (tid & 3) << 2;
      float4 v = *(const float4*)(P + pb + (size_t)(r0 + rr) * NIND + jb + j0 + jj);
      As[rr][jj] = v.x; As[rr][jj+1] = v.y; As[rr][jj+2] = v.z; As[rr][jj+3] = v.w;
      #pragma unroll
      for (int t = 0; t < 2; ++t) {
        int f = tid + t * 256;
        int r2 = f >> 2, j2 = (f & 3) << 2;
        float4 u = *(const float4*)(invb + (size_t)r2 * 128 + j0 + j2);
        Ls[r2][j2] = u.x; Ls[r2][j2+1] = u.y; Ls[r2][j2+2] = u.z; Ls[r2][j2+3] = u.w;
      }
    }
    __syncthreads();
    #pragma unroll
    for (int qq = 0; qq < 16; ++qq) {
      float a[4];
      #pragma unroll
      for (int r = 0; r < 4; ++r) a[r] = As[tr*4+r][qq];
      #pragma unroll
      for (int c = 0; c < 8; ++c) {
        float lv = Ls[tc*8+c][qq];
        #pragma unroll
        for (int r = 0; r < 4; ++r) acc[r][c] += a[r] * lv;
      }
    }
    __syncthreads();
  }
  #pragma unroll
  for (int r = 0; r < 4; ++r) {
    #pragma unroll
    for (int c0 = 0; c0 < 8; c0 += 4) {
      float4 o = make_float4(acc[r][c0], acc[r][c0+1], acc[r][c0+2], acc[r][c0+3]);
      *(float4*)(P + pb + (size_t)(r0 + tr*4 + r) * NIND + jb + tc*8 + c0) = o;
    }
  }
}

// K6: trailing update A22 -= L21 L21^T
__global__ __launch_bounds__(256) void syrk_kernel(float* __restrict__ P, int it)
{
  __shared__ float Pa[64][17];
  __shared__ float Pb[64][17];
  int p = blockIdx.x;
  int a = (int)((sqrtf(8.f * p + 1.f) - 1.f) * 0.5f);
  while ((a + 1) * (a + 2) / 2 <= p) ++a;
  while (a * (a + 1) / 2 > p) --a;
  int b = p - a * (a + 1) / 2;
  const int tbase = (it + 1) * 2;
  const int r0 = (tbase + a) * 64, c0 = (tbase + b) * 64;
  const int jb = it * 128;
  const int k = blockIdx.y;
  const size_t pb = (size_t)k * NIND * NIND;
  const int tid = threadIdx.x, tr = tid >> 4, tc = tid & 15;
  float acc[4][4] = {};
  for (int j0 = 0; j0 < 128; j0 += 16) {
    int rr = tid >> 2, jj = (tid & 3) << 2;
    float4 v = *(const float4*)(P + pb + (size_t)(r0 + rr) * NIND + jb + j0 + jj);
    Pa[rr][jj] = v.x; Pa[rr][jj+1] = v.y; Pa[rr][jj+2] = v.z; Pa[rr][jj+3] = v.w;
    float4 u = *(const float4*)(P + pb + (size_t)(c0 + rr) * NIND + jb + j0 + jj);
    Pb[rr][jj] = u.x; Pb[rr][jj+1] = u.y; Pb[rr][jj+2] = u.z; Pb[rr][jj+3] = u.w;
    __syncthreads();
    #pragma unroll
    for (int qq = 0; qq < 16; ++qq) {
      float av[4], bv[4];
      #pragma unroll
      for (int r = 0; r < 4; ++r) av[r] = Pa[tr*4+r][qq];
      #pragma unroll
      for (int c = 0; c < 4; ++c) bv[c] = Pb[tc*4+c][qq];
      #pragma unroll
      for (int r = 0; r < 4; ++r)
        #pragma unroll
        for (int c = 0; c < 4; ++c) acc[r][c] += av[r] * bv[c];
    }
    __syncthreads();
  }
  #pragma unroll
  for (int r = 0; r < 4; ++r) {
    float* dst = P + pb + (size_t)(r0 + tr*4 + r) * NIND + c0 + tc*4;
    float4 cur = *(float4*)dst;
    cur.x -= acc[r][0]; cur.y -= acc[r][1]; cur.z -= acc[r][2]; cur.w -= acc[r][3];
    *(float4*)dst = cur;
  }
}

// K7: blocked forward substitution step I
__global__ __launch_bounds__(256) void solve_kernel(
    const float* __restrict__ P, const float* __restrict__ invL,
    const float* __restrict__ phiT, float* __restrict__ Y,
    float* __restrict__ out, int I, int kbase)
{
  __shared__ float Ls[128][17];
  __shared__ float Ys[16][68];
  __shared__ float Ts[128][68];
  __shared__ float pv[16][64];
  const int ks = blockIdx.y, k = kbase + ks;
  const int b0 = blockIdx.x * 64;
  const int tid = threadIdx.x, tr = tid >> 4, tc = tid & 15;
  const size_t pb = (size_t)k * NIND * NIND;
  float acc[8][4];
  #pragma unroll
  for (int rr = 0; rr < 8; ++rr) {
    float4 v = *(const float4*)(phiT + (size_t)(I*128 + tr*8 + rr) * BATCH + b0 + tc*4);
    acc[rr][0] = v.x; acc[rr][1] = v.y; acc[rr][2] = v.z; acc[rr][3] = v.w;
  }
  for (int J = 0; J < I; ++J) {
    const size_t yb = (size_t)ks * NIND * BATCH + (size_t)(J * 128) * BATCH;
    for (int j0 = 0; j0 < 128; j0 += 16) {
      #pragma unroll
      for (int t = 0; t < 2; ++t) {
        int f = tid + t * 256;
        int r2 = f >> 2, j2 = (f & 3) << 2;
        float4 u = *(const float4*)(P + pb + (size_t)(I*128 + r2) * NIND + J*128 + j0 + j2);
        Ls[r2][j2] = u.x; Ls[r2][j2+1] = u.y; Ls[r2][j2+2] = u.z; Ls[r2][j2+3] = u.w;
      }
      {
        int jj = tid >> 4, c4 = (tid & 15) << 2;
        *(float4*)(&Ys[jj][c4]) = *(const float4*)(Y + yb + (size_t)(j0 + jj) * BATCH + b0 + c4);
      }
      __syncthreads();
      #pragma unroll
      for (int qq = 0; qq < 16; ++qq) {
        float yv[4];
        #pragma unroll
        for (int c = 0; c < 4; ++c) yv[c] = Ys[qq][tc*4+c];
        #pragma unroll
        for (int rr = 0; rr < 8; ++rr) {
          float lv = Ls[tr*8+rr][qq];
          #pragma unroll
          for (int c = 0; c < 4; ++c) acc[rr][c] -= lv * yv[c];
        }
      }
      __syncthreads();
    }
  }
  #pragma unroll
  for (int rr = 0; rr < 8; ++rr)
    *(float4*)(&Ts[tr*8+rr][tc*4]) = make_float4(acc[rr][0], acc[rr][1], acc[rr][2], acc[rr][3]);
  __syncthreads();
  const float* invb = invL + ((size_t)k * 8 + I) * 16384;
  float oa[8][4] = {};
  for (int j0 = 0; j0 < 128; j0 += 16) {
    #pragma unroll
    for (int t = 0; t < 2; ++t) {
      int f = tid + t * 256;
      int r2 = f >> 2, j2 = (f & 3) << 2;
      float4 u = *(const float4*)(invb + (size_t)r2 * 128 + j0 + j2);
      Ls[r2][j2] = u.x; Ls[r2][j2+1] = u.y; Ls[r2][j2+2] = u.z; Ls[r2][j2+3] = u.w;
    }
    __syncthreads();
    #pragma unroll
    for (int qq = 0; qq < 16; ++qq) {
      float4 t4 = *(const float4*)(&Ts[j0+qq][tc*4]);
      float tv[4] = {t4.x, t4.y, t4.z, t4.w};
      #pragma unroll
      for (int rr = 0; rr < 8; ++rr) {
        float lv = Ls[tr*8+rr][qq];
        #pragma unroll
        for (int c = 0; c < 4; ++c) oa[rr][c] += lv * tv[c];
      }
    }
    __syncthreads();
  }
  const size_t yo = (size_t)ks * NIND * BATCH + (size_t)(I * 128) * BATCH;
  float vp[4] = {0.f, 0.f, 0.f, 0.f};
  #pragma unroll
  for (int rr = 0; rr < 8; ++rr) {
    *(float4*)(Y + yo + (size_t)(tr*8 + rr) * BATCH + b0 + tc*4) =
        make_float4(oa[rr][0], oa[rr][1], oa[rr][2], oa[rr][3]);
    #pragma unroll
    for (int c = 0; c < 4; ++c) vp[c] += oa[rr][c] * oa[rr][c];
  }
  #pragma unroll
  for (int c = 0; c < 4; ++c) pv[tr][tc*4+c] = vp[c];
  __syncthreads();
  if (tid < 64) {
    float s = 0.f;
    #pragma unroll
    for (int t = 0; t < 16; ++t) s += pv[t][tid];
    out[BATCH * NCLS + (size_t)(b0 + tid) * NCLS + k] += s;
  }
}

extern "C" void kernel_launch(void* const* d_in, const int* in_sizes, int n_in,
                              void* d_out, int out_size, void* d_ws, size_t ws_size,
                              hipStream_t stream)
{
  (void)in_sizes; (void)n_in;
  const float* x   = (const float*)d_in[0];
  const float* rw  = (const float*)d_in[1];
  const float* rb  = (const float*)d_in[2];
  const float* bw  = (const float*)d_in[3];
  const float* bb  = (const float*)d_in[4];
  const float* prc = (const float*)d_in[5];
  float* out = (float*)d_out;
  char* ws = (char*)d_ws;
  size_t off = 0;
  auto alloc = [&](size_t bytes) -> void* {
    void* p = ws + off;
    off = (off + bytes + 255) & ~(size_t)255;
    return p;
  };
  float* phi   = (float*)alloc((size_t)BATCH * NIND * 4);
  float* phiT  = (float*)alloc((size_t)NIND * BATCH * 4);
  u16*   phiTB = (u16*)  alloc((size_t)NIND * BATCH * 2);
  float* wmat  = (float*)alloc((size_t)NCLS * BATCH * 4);
  float* P     = (float*)alloc((size_t)NCLS * NIND * NIND * 4);
  float* invL  = (float*)alloc((size_t)NCLS * 8 * 128 * 128 * 4);
  // union region: phiW (64MB, used only before solve) aliased with Y (kc*8MB)
  const size_t per = (size_t)NIND * BATCH * 4;          // 8MB
  const size_t rem = (ws_size > off) ? (ws_size - off) : 0;
  int kc = 1;
  if (rem >= 16 * per) kc = 16;
  else if (rem >= 8 * per) kc = 8;
  else if (rem >= 4 * per) kc = 4;
  else if (rem >= 2 * per) kc = 2;
  u16*   phiW = (u16*)(ws + off);     // needs 64MB = 8*per (rem >= 64MB expected)
  float* Y    = (float*)(ws + off);   // same address; phiW dead before solve

  hipMemsetAsync(d_out, 0, (size_t)out_size * sizeof(float), stream);
  phi_kernel<<<dim3(BATCH/64, NIND/64), 256, 0, stream>>>(x, rw, rb, phi, phiT, phiTB);
  logits_kernel<<<dim3(BATCH), 256, 0, stream>>>(phi, bw, bb, out, wmat);
  scalew_kernel<<<dim3(1024, NCLS), 256, 0, stream>>>(phiT, wmat, phiW);
  gram_kernel<<<dim3(36, NCLS), 256, 0, stream>>>(phiW, phiTB, prc, P);
  for (int it = 0; it < 8; ++it) {
    potrf_kernel<<<dim3(NCLS), 1024, 0, stream>>>(P, invL, it);
    if (it < 7) {
      trsm_kernel<<<dim3((7 - it) * 2, NCLS), 256, 0, stream>>>(P, invL, it);
      int n = 14 - 2 * it;
      syrk_kernel<<<dim3(n * (n + 1) / 2, NCLS), 256, 0, stream>>>(P, it);
    }
  }
  for (int kb = 0; kb < NCLS; kb += kc) {
    for (int I = 0; I < 8; ++I) {
      solve_kernel<<<dim3(BATCH/64, kc), 256, 0, stream>>>(P, invL, phiT, Y, out, I, kb);
    }
  }
}